// Round 4
// baseline (5715.283 us; speedup 1.0000x reference)
//
#include <hip/hip_runtime.h>

// GRU encoder: B=128, K=512, I=512, H=512.
// R10: single-dispatch fully-fused GRU.
//   - 64 blocks x 256 threads; block (ug,bg) owns units u0..u0+31 (x2 u16 waves)
//     and rows b0..b0+31 (x2 mt domains). All 512 steps in one kernel.
//   - h exchange: tagged u64 units {tag32 | bf16-pair} via relaxed AGENT atomics.
//     No flags, no producer drain: publish is fire-and-forget; consumers poll the
//     data itself (sampled-tag spin, then bulk 64x8B load + full tag validate).
//     Parity double-buffer + step dependency chain make overwrite-before-read
//     impossible; memset(0xFF) prevents stale-tag aliasing across iterations.
//   - x-gate GEMM fused into rec blocks: W_ih slice (96KB) + vis slab (32KB) in
//     XOR-swizzled LDS ((row&7)<<3 in shorts — kills the 16-way bank conflict of
//     [r][512] bf16 row-major B-fragment reads). The 48 x-MFMAs/step/wave run
//     between publish(kg-1) and poll(kg-1), hiding the exchange latency.
//   - No GEMM role, no xg buffers, no chunked dispatches. Workspace = 512KB.

#define HBT_BYTES (2 * 128 * 256 * 8)   // 524,288 B of tagged h pairs

typedef float  floatx4 __attribute__((ext_vector_type(4)));
typedef short  shortx8 __attribute__((ext_vector_type(8)));

__device__ __forceinline__ unsigned short f2bf(float f) {
    unsigned int uu = __float_as_uint(f);
    uu = (uu + 0x7FFFu + ((uu >> 16) & 1u)) >> 16;   // RNE; finite normals only
    return (unsigned short)uu;
}

__global__ __launch_bounds__(256, 1)
void gru_rec(const float* __restrict__ vis, const float* __restrict__ Wih,
             const float* __restrict__ bih, const float* __restrict__ Whh,
             const float* __restrict__ bhh,
             unsigned long long* __restrict__ hbt, float* __restrict__ out) {
    __shared__ unsigned short Wlds[96 * 512];   // 96KB: W_ih rows {g*32+lu} x 512 K, swizzled
    __shared__ unsigned short Vlds[32 * 512];   // 32KB: vis slab 32 rows x 512 I, swizzled

    const int bx = blockIdx.x, t = threadIdx.x;
    const int wave = t >> 6, lane = t & 63, quad = lane >> 4, l16 = lane & 15;
    const int ug = bx & 15, bg = bx >> 4;
    const int u0 = ug * 32, b0 = bg * 32;
    const int mt = wave & 1, u16 = wave >> 1;
    const int b_base = b0 + mt * 16 + quad * 4;   // C rows = b_base + reg
    const int u = u0 + u16 * 16 + l16;            // this lane's unit column
    const int rrow = b0 + mt * 16 + l16;          // exchange A-fragment row

    // ---- one-time: W_hh B-fragments -> VGPRs (192 regs) ----
    shortx8 w[3][16];
    #pragma unroll
    for (int g = 0; g < 3; ++g) {
        #pragma unroll
        for (int kt = 0; kt < 16; ++kt) {
            const float* p = Whh + ((size_t)(g * 512 + u)) * 512 + kt * 32 + quad * 8;
            float4 a = *(const float4*)p;
            float4 b = *(const float4*)(p + 4);
            shortx8 v;
            v[0] = (short)f2bf(a.x); v[1] = (short)f2bf(a.y);
            v[2] = (short)f2bf(a.z); v[3] = (short)f2bf(a.w);
            v[4] = (short)f2bf(b.x); v[5] = (short)f2bf(b.y);
            v[6] = (short)f2bf(b.z); v[7] = (short)f2bf(b.w);
            w[g][kt] = v;
        }
    }
    const float bhr = bhh[u], bhz = bhh[512 + u], bhn = bhh[1024 + u];
    const float bir = bih[u], biz = bih[512 + u], bin = bih[1024 + u];

    // ---- one-time: W_ih slice -> LDS (swizzled) ----
    for (int i = t; i < 96 * 128; i += 256) {
        const int r = i >> 7, cq = i & 127;          // LDS row, float4-chunk
        const int g = r >> 5, lu = r & 31;
        const float* p = Wih + ((size_t)(g * 512 + u0 + lu)) * 512 + cq * 4;
        float4 vv = *(const float4*)p;
        ushort4 b4;
        b4.x = f2bf(vv.x); b4.y = f2bf(vv.y); b4.z = f2bf(vv.z); b4.w = f2bf(vv.w);
        *(ushort4*)&Wlds[r * 512 + ((cq * 4) ^ ((r & 7) << 3))] = b4;
    }

    float hp[4] = {0.f, 0.f, 0.f, 0.f};

    // ---- preload vis slab k=0 into regs ----
    const int vrow = t >> 7;                       // 0..1 (row = vrow + it*2)
    const int vcq = t & 127;
    float4 S[16];
    {
        const float* vp = vis + ((size_t)(b0 + vrow) * 512 + 0) * 512 + vcq * 4;
        #pragma unroll
        for (int it = 0; it < 16; ++it)
            S[it] = *(const float4*)(vp + (size_t)it * (2 * 512 * 512));
    }

    const int ra = mt * 16 + l16, xra = (ra & 7) << 3;     // vis A-frag row + swizzle
    const int rb = u16 * 16 + l16, xrb = (rb & 7) << 3;    // W_ih B-frag row + swizzle

    for (int kg = 0; kg < 512; ++kg) {
        // ---- write vis slab(kg) (S loaded last iteration) ----
        __syncthreads();                           // prior x-reads of Vlds done
        #pragma unroll
        for (int it = 0; it < 16; ++it) {
            const int r = vrow + it * 2;
            ushort4 b4;
            b4.x = f2bf(S[it].x); b4.y = f2bf(S[it].y);
            b4.z = f2bf(S[it].z); b4.w = f2bf(S[it].w);
            *(ushort4*)&Vlds[r * 512 + ((vcq * 4) ^ ((r & 7) << 3))] = b4;
        }
        __syncthreads();

        // ---- x-gates xg(kg): 48 MFMAs from LDS (fills the exchange latency slot) ----
        floatx4 xR = {0,0,0,0}, xZ = {0,0,0,0}, xN = {0,0,0,0};
        #pragma unroll
        for (int kt = 0; kt < 16; ++kt) {
            const int co = kt * 32 + quad * 8;
            shortx8 a  = *(const shortx8*)&Vlds[ra * 512 + (co ^ xra)];
            shortx8 bR = *(const shortx8*)&Wlds[rb * 512 + (co ^ xrb)];
            shortx8 bZ = *(const shortx8*)&Wlds[(32 + rb) * 512 + (co ^ xrb)];
            shortx8 bN = *(const shortx8*)&Wlds[(64 + rb) * 512 + (co ^ xrb)];
            xR = __builtin_amdgcn_mfma_f32_16x16x32_bf16(a, bR, xR, 0, 0, 0);
            xZ = __builtin_amdgcn_mfma_f32_16x16x32_bf16(a, bZ, xZ, 0, 0, 0);
            xN = __builtin_amdgcn_mfma_f32_16x16x32_bf16(a, bN, xN, 0, 0, 0);
        }

        // ---- consume h(kg-1): tagged u64 units ----
        union LU { unsigned long long v; unsigned int d[2]; };
        LU L[16][4];
        if (kg > 0) {
            const unsigned int expv = (unsigned int)(kg - 1);
            const size_t pbase = (size_t)((kg - 1) & 1) * 32768;
            // stage 1: sampled-tag spin (1 load/lane, one sample per producer wave)
            const unsigned long long* sp = hbt + pbase + (size_t)rrow * 256
                                              + ((lane & 31) >> 1) * 16 + (lane & 1) * 8;
            for (;;) {
                unsigned int tg = (unsigned int)(__hip_atomic_load(sp, __ATOMIC_RELAXED,
                                                 __HIP_MEMORY_SCOPE_AGENT) >> 32);
                if (__ballot(tg != expv) == 0ull) break;
                __builtin_amdgcn_s_sleep(1);
            }
            // stage 2: bulk load + full per-unit tag validation (usually one pass)
            const unsigned long long* hbp = hbt + pbase + (size_t)rrow * 256 + quad * 4;
            for (;;) {
                #pragma unroll
                for (int kt = 0; kt < 16; ++kt) {
                    #pragma unroll
                    for (int j = 0; j < 4; ++j)
                        L[kt][j].v = __hip_atomic_load(hbp + kt * 16 + j,
                                        __ATOMIC_RELAXED, __HIP_MEMORY_SCOPE_AGENT);
                }
                unsigned int err = 0u;
                #pragma unroll
                for (int kt = 0; kt < 16; ++kt) {
                    #pragma unroll
                    for (int j = 0; j < 4; ++j) err |= (L[kt][j].d[1] ^ expv);
                }
                if (__ballot(err != 0u) == 0ull) break;
                __builtin_amdgcn_s_sleep(1);
            }
        } else {
            #pragma unroll
            for (int kt = 0; kt < 16; ++kt) {
                #pragma unroll
                for (int j = 0; j < 4; ++j) L[kt][j].v = 0ull;
            }
        }

        // ---- h-MFMA: 48 MFMAs, af built per-kt from u64 lo-halves (transient) ----
        floatx4 aR = {0,0,0,0}, aZ = {0,0,0,0}, aN = {0,0,0,0};
        #pragma unroll
        for (int kt = 0; kt < 16; ++kt) {
            union { unsigned int d[4]; shortx8 v; } af;
            af.d[0] = L[kt][0].d[0]; af.d[1] = L[kt][1].d[0];
            af.d[2] = L[kt][2].d[0]; af.d[3] = L[kt][3].d[0];
            aR = __builtin_amdgcn_mfma_f32_16x16x32_bf16(af.v, w[0][kt], aR, 0, 0, 0);
            aZ = __builtin_amdgcn_mfma_f32_16x16x32_bf16(af.v, w[1][kt], aZ, 0, 0, 0);
            aN = __builtin_amdgcn_mfma_f32_16x16x32_bf16(af.v, w[2][kt], aN, 0, 0, 0);
        }

        // ---- prefetch vis slab(kg+1); RT hides under act/publish/bar_A ----
        {
            const int kn = (kg < 511) ? kg + 1 : 511;
            const float* vp = vis + ((size_t)(b0 + vrow) * 512 + kn) * 512 + vcq * 4;
            #pragma unroll
            for (int it = 0; it < 16; ++it)
                S[it] = *(const float4*)(vp + (size_t)it * (2 * 512 * 512));
        }

        // ---- activations + tagged publish (fire-and-forget) ----
        unsigned long long* hdst = hbt + (size_t)(kg & 1) * 32768;
        const unsigned long long tagv = ((unsigned long long)(unsigned int)kg) << 32;
        #pragma unroll
        for (int reg = 0; reg < 4; ++reg) {
            const float r = 1.f / (1.f + __expf(-(xR[reg] + bir + aR[reg] + bhr)));
            const float z = 1.f / (1.f + __expf(-(xZ[reg] + biz + aZ[reg] + bhz)));
            const float nv = xN[reg] + bin + r * (aN[reg] + bhn);
            const float n = 1.f - 2.f / (__expf(2.f * nv) + 1.f);   // fast tanh
            const float h = (1.f - z) * n + z * hp[reg];
            hp[reg] = h;
            const float h_odd = __shfl_xor(h, 1);
            if (!(lane & 1)) {
                unsigned long long val = tagv |
                    (unsigned long long)((unsigned int)f2bf(h) |
                                         ((unsigned int)f2bf(h_odd) << 16));
                __hip_atomic_store(hdst + (size_t)(b_base + reg) * 256 + (u >> 1), val,
                                   __ATOMIC_RELAXED, __HIP_MEMORY_SCOPE_AGENT);
            }
            if (kg == 511) out[(size_t)(b_base + reg) * 512 + u] = h;
        }
    }
}

extern "C" void kernel_launch(void* const* d_in, const int* in_sizes, int n_in,
                              void* d_out, int out_size, void* d_ws, size_t ws_size,
                              hipStream_t stream) {
    const float* vis = (const float*)d_in[0];
    const float* Wih = (const float*)d_in[1];
    const float* Whh = (const float*)d_in[2];
    const float* bih = (const float*)d_in[3];
    const float* bhh = (const float*)d_in[4];
    float* out = (float*)d_out;

    unsigned long long* hbt = (unsigned long long*)d_ws;

    // 0xFF tags (0xFFFFFFFF) never match any step 0..511; re-armed every iteration.
    hipMemsetAsync(hbt, 0xFF, HBT_BYTES, stream);

    gru_rec<<<64, 256, 0, stream>>>(vis, Wih, bih, Whh, bhh, hbt, out);
}

// Round 5
// 4458.889 us; speedup vs baseline: 1.2818x; 1.2818x over previous
//
#include <hip/hip_runtime.h>

// GRU encoder: B=128, K=512, I=512, H=512.
// R11: serialized two-kernel structure + tagged exchange.
//   - Roles alternate on the stream (G0,R0,G1,R1,...): zero contention, the
//     R8 overlap was net-negative (contention cost > GEMM hiding benefit).
//   - gemm_xg: grid 1536 (1-2 tiles/block, ~6 blocks/CU) computes 64 steps of
//     x-gates into ONE xg buffer (serialization makes double-buffer pointless).
//   - gru_rec: 64 blocks, tagged u64 h-exchange (R10-validated protocol: data
//     carries its step tag; no flags, no producer drain). Bulk consume via 32
//     pipelined global_load_dwordx4 sc0 sc1 + full tag validation loop.
//     W_hh lives in XOR-swizzled LDS (96KB) instead of VGPRs: frees 192 regs
//     so the 128-reg tagged-load burst fits with NO scratch spills, and the
//     step loop has NO barriers (waves fully independent).
//   - 'out' doubles as the f32 h-state carry between rec dispatches.
// Workspace: [ xg 50,331,648 | hbt 524,288 ] = 50,855,936 B.

#define CH 64
#define XG_BYTES (CH * 128 * 1536 * 4)
#define HBT_BYTES (2 * 128 * 256 * 8)

typedef float  floatx4 __attribute__((ext_vector_type(4)));
typedef short  shortx8 __attribute__((ext_vector_type(8)));
typedef unsigned int uintx4 __attribute__((ext_vector_type(4)));

__device__ __forceinline__ unsigned short f2bf(float f) {
    unsigned int uu = __float_as_uint(f);
    uu = (uu + 0x7FFFu + ((uu >> 16) & 1u)) >> 16;   // RNE; finite normals only
    return (unsigned short)uu;
}

// ===================== REC KERNEL =====================
__global__ __launch_bounds__(256, 1)
void gru_rec(const float* __restrict__ xgR, const float* __restrict__ Whh,
             const float* __restrict__ bhh,
             unsigned long long* __restrict__ hbt, float* __restrict__ out,
             int kg0) {
    __shared__ unsigned short Wl[96 * 512];   // 96KB: rows g*32+lu, swizzled bf16 W_hh slice

    const int bx = blockIdx.x, t = threadIdx.x;
    const int wave = t >> 6, lane = t & 63, quad = lane >> 4, l16 = lane & 15;
    const int ug = bx & 15, bg = bx >> 4;
    const int u0 = ug * 32, b0 = bg * 32;
    const int mt = wave & 1, u16 = wave >> 1;
    const int b_base = b0 + mt * 16 + quad * 4;   // C rows = b_base + reg
    const int u = u0 + u16 * 16 + l16;            // this lane's unit column
    const int rrow = b0 + mt * 16 + l16;          // exchange A-fragment row

    // ---- stage W_hh slice -> LDS (bf16, swizzled) ----
    for (int i = t; i < 96 * 128; i += 256) {
        const int r = i >> 7, cq = i & 127;       // LDS row (g*32+lu), float4-chunk
        const int g = r >> 5, lu = r & 31;
        const float* p = Whh + ((size_t)(g * 512 + u0 + lu)) * 512 + cq * 4;
        float4 vv = *(const float4*)p;
        ushort4 b4;
        b4.x = f2bf(vv.x); b4.y = f2bf(vv.y); b4.z = f2bf(vv.z); b4.w = f2bf(vv.w);
        *(ushort4*)&Wl[r * 512 + ((cq * 4) ^ ((r & 7) << 3))] = b4;
    }
    __syncthreads();

    const float bhr = bhh[u], bhz = bhh[512 + u], bhn = bhh[1024 + u];
    const int rb = u16 * 16 + l16, xrw = (rb & 7) << 3;   // B-frag LDS row + swizzle

    float hp[4];
    if (kg0 == 0) {
        hp[0] = hp[1] = hp[2] = hp[3] = 0.f;
    } else {
        #pragma unroll
        for (int reg = 0; reg < 4; ++reg) hp[reg] = out[(size_t)(b_base + reg) * 512 + u];
    }

    for (int s = 0; s < CH; ++s) {
        const int kg = kg0 + s;
        // x-gate loads issue early; exchange poll hides their latency
        float xr[4], xz[4], xn[4];
        #pragma unroll
        for (int reg = 0; reg < 4; ++reg) {
            const float* xgp = xgR + ((size_t)s * 128 + b_base + reg) * 1536 + u;
            xr[reg] = xgp[0]; xz[reg] = xgp[512]; xn[reg] = xgp[1024];
        }

        union { unsigned int d[4]; shortx8 v; } af[16];
        if (kg > 0) {
            const unsigned int expv = (unsigned int)(kg - 1);
            const size_t pbase = (size_t)((kg - 1) & 1) * 32768;
            // stage 1: sampled-tag spin (1 load/lane, one sample per producer wave)
            const unsigned long long* sp = hbt + pbase + (size_t)rrow * 256
                                              + ((lane & 31) >> 1) * 16 + (lane & 1) * 8;
            for (;;) {
                unsigned int tg = (unsigned int)(__hip_atomic_load(sp, __ATOMIC_RELAXED,
                                                 __HIP_MEMORY_SCOPE_AGENT) >> 32);
                if (__ballot(tg != expv) == 0ull) break;
                __builtin_amdgcn_s_sleep(1);
            }
            // stage 2: 32 pipelined dwordx4 (tagged u64 pairs) + full tag validation
            const unsigned long long* hbp = hbt + pbase + (size_t)rrow * 256 + quad * 4;
            union { uintx4 v; unsigned int d[4]; } Tq[32];
            for (;;) {
                #define LDT(i, OFF) asm volatile("global_load_dwordx4 %0, %1, off offset:" OFF " sc0 sc1" \
                        : "=v"(Tq[i].v) : "v"(hbp) : "memory");
                LDT(0,"0")     LDT(1,"16")    LDT(2,"128")   LDT(3,"144")
                LDT(4,"256")   LDT(5,"272")   LDT(6,"384")   LDT(7,"400")
                LDT(8,"512")   LDT(9,"528")   LDT(10,"640")  LDT(11,"656")
                LDT(12,"768")  LDT(13,"784")  LDT(14,"896")  LDT(15,"912")
                LDT(16,"1024") LDT(17,"1040") LDT(18,"1152") LDT(19,"1168")
                LDT(20,"1280") LDT(21,"1296") LDT(22,"1408") LDT(23,"1424")
                LDT(24,"1536") LDT(25,"1552") LDT(26,"1664") LDT(27,"1680")
                LDT(28,"1792") LDT(29,"1808") LDT(30,"1920") LDT(31,"1936")
                #undef LDT
                asm volatile("s_waitcnt vmcnt(0)" ::: "memory");
                __builtin_amdgcn_sched_barrier(0);
                unsigned int err = 0u;
                #pragma unroll
                for (int i = 0; i < 32; ++i)
                    err |= (Tq[i].d[1] ^ expv) | (Tq[i].d[3] ^ expv);
                if (__ballot(err != 0u) == 0ull) break;
                __builtin_amdgcn_s_sleep(1);
            }
            #pragma unroll
            for (int kt = 0; kt < 16; ++kt) {
                af[kt].d[0] = Tq[2 * kt].d[0];     af[kt].d[1] = Tq[2 * kt].d[2];
                af[kt].d[2] = Tq[2 * kt + 1].d[0]; af[kt].d[3] = Tq[2 * kt + 1].d[2];
            }
        } else {
            #pragma unroll
            for (int kt = 0; kt < 16; ++kt) {
                af[kt].d[0] = 0u; af[kt].d[1] = 0u; af[kt].d[2] = 0u; af[kt].d[3] = 0u;
            }
        }

        // ---- h-MFMA: 48 MFMAs; B-fragments streamed from swizzled LDS ----
        floatx4 aR = {0,0,0,0}, aZ = {0,0,0,0}, aN = {0,0,0,0};
        #pragma unroll
        for (int kt = 0; kt < 16; ++kt) {
            const int co = (kt * 32 + quad * 8) ^ xrw;
            shortx8 bR = *(const shortx8*)&Wl[(size_t)rb * 512 + co];
            shortx8 bZ = *(const shortx8*)&Wl[(size_t)(32 + rb) * 512 + co];
            shortx8 bN = *(const shortx8*)&Wl[(size_t)(64 + rb) * 512 + co];
            aR = __builtin_amdgcn_mfma_f32_16x16x32_bf16(af[kt].v, bR, aR, 0, 0, 0);
            aZ = __builtin_amdgcn_mfma_f32_16x16x32_bf16(af[kt].v, bZ, aZ, 0, 0, 0);
            aN = __builtin_amdgcn_mfma_f32_16x16x32_bf16(af[kt].v, bN, aN, 0, 0, 0);
        }

        // ---- activations + tagged publish (fire-and-forget, no drain) ----
        unsigned long long* hdst = hbt + (size_t)(kg & 1) * 32768;
        const unsigned long long tagv = ((unsigned long long)(unsigned int)kg) << 32;
        #pragma unroll
        for (int reg = 0; reg < 4; ++reg) {
            const float r = 1.f / (1.f + __expf(-(xr[reg] + aR[reg] + bhr)));
            const float z = 1.f / (1.f + __expf(-(xz[reg] + aZ[reg] + bhz)));
            const float nv = xn[reg] + r * (aN[reg] + bhn);
            const float n = 1.f - 2.f / (__expf(2.f * nv) + 1.f);   // fast tanh
            const float h = (1.f - z) * n + z * hp[reg];
            hp[reg] = h;
            const float h_odd = __shfl_xor(h, 1);
            if (!(lane & 1)) {
                unsigned long long val = tagv |
                    (unsigned long long)((unsigned int)f2bf(h) |
                                         ((unsigned int)f2bf(h_odd) << 16));
                __hip_atomic_store(hdst + (size_t)(b_base + reg) * 256 + (u >> 1), val,
                                   __ATOMIC_RELAXED, __HIP_MEMORY_SCOPE_AGENT);
            }
        }
    }

    // running h -> out (acts as hstate carry; final dispatch leaves h[511] here)
    #pragma unroll
    for (int reg = 0; reg < 4; ++reg)
        out[(size_t)(b_base + reg) * 512 + u] = hp[reg];
}

// ===================== GEMM KERNEL (x-gates for one 64-step chunk) =====================
__global__ __launch_bounds__(256)
void gemm_xg(const float* __restrict__ vis, const float* __restrict__ Wih,
             const float* __restrict__ bih, float* __restrict__ xgW, int gemm_kg0) {
    __shared__ unsigned short Ast[64][40];
    __shared__ unsigned short Bst[64][40];

    const int t = threadIdx.x;
    const int wave = t >> 6, lane = t & 63, quad = lane >> 4, l16 = lane & 15;

    for (int T = blockIdx.x; T < 24 * 128; T += gridDim.x) {   // 24 g-tiles x 128 m-tiles
        const int g0 = (T % 24) * 64;
        const int m0 = (T / 24) * 64;            // chunk-local m = kc*128 + b
        const int kc = m0 >> 7;                  // 0..63
        const int b0 = m0 & 127;
        const int kg = gemm_kg0 + kc;

        floatx4 acc[4] = {{0,0,0,0},{0,0,0,0},{0,0,0,0},{0,0,0,0}};

        for (int ki = 0; ki < 16; ++ki) {
            const int i0 = ki * 32;
            #pragma unroll
            for (int rep = 0; rep < 2; ++rep) {
                const int r = (t >> 3) + rep * 32;
                const int c = (t & 7) * 4;
                float4 av = *(const float4*)(vis + ((size_t)(b0 + r) * 512 + kg) * 512 + i0 + c);
                ushort4 ab; ab.x = f2bf(av.x); ab.y = f2bf(av.y); ab.z = f2bf(av.z); ab.w = f2bf(av.w);
                *(ushort4*)&Ast[r][c] = ab;
                float4 bv = *(const float4*)(Wih + (size_t)(g0 + r) * 512 + i0 + c);
                ushort4 bb; bb.x = f2bf(bv.x); bb.y = f2bf(bv.y); bb.z = f2bf(bv.z); bb.w = f2bf(bv.w);
                *(ushort4*)&Bst[r][c] = bb;
            }
            __syncthreads();
            shortx8 afr = *(const shortx8*)(&Ast[wave * 16 + l16][quad * 8]);
            #pragma unroll
            for (int nb = 0; nb < 4; ++nb) {
                shortx8 bfr = *(const shortx8*)(&Bst[nb * 16 + l16][quad * 8]);
                acc[nb] = __builtin_amdgcn_mfma_f32_16x16x32_bf16(afr, bfr, acc[nb], 0, 0, 0);
            }
            __syncthreads();
        }
        #pragma unroll
        for (int nb = 0; nb < 4; ++nb) {
            const int g = g0 + nb * 16 + l16;
            const float bi = bih[g];
            #pragma unroll
            for (int reg = 0; reg < 4; ++reg) {
                const int m = m0 + wave * 16 + quad * 4 + reg;
                xgW[(size_t)m * 1536 + g] = acc[nb][reg] + bi;
            }
        }
    }
}

extern "C" void kernel_launch(void* const* d_in, const int* in_sizes, int n_in,
                              void* d_out, int out_size, void* d_ws, size_t ws_size,
                              hipStream_t stream) {
    const float* vis = (const float*)d_in[0];
    const float* Wih = (const float*)d_in[1];
    const float* Whh = (const float*)d_in[2];
    const float* bih = (const float*)d_in[3];
    const float* bhh = (const float*)d_in[4];
    float* out = (float*)d_out;

    char* ws = (char*)d_ws;
    float* xg = (float*)ws;
    unsigned long long* hbt = (unsigned long long*)(ws + XG_BYTES);

    // 0xFF tags (0xFFFFFFFF) never match any step 0..511; re-armed every iteration
    // (prevents stale-tag aliasing at the parity buffer across bench replays).
    hipMemsetAsync(hbt, 0xFF, HBT_BYTES, stream);

    // Serialized alternation: G0, R0, G1, R1, ..., G7, R7. Single xg buffer —
    // stream order guarantees G(c+1) only overwrites after R(c) finished.
    gemm_xg<<<1536, 256, 0, stream>>>(vis, Wih, bih, xg, 0);
    for (int c = 0; c < 8; ++c) {
        gru_rec<<<64, 256, 0, stream>>>(xg, Whh, bhh, hbt, out, c * CH);
        if (c < 7)
            gemm_xg<<<1536, 256, 0, stream>>>(vis, Wih, bih, xg, (c + 1) * CH);
    }
}

// Round 6
// 4255.668 us; speedup vs baseline: 1.3430x; 1.0478x over previous
//
#include <hip/hip_runtime.h>

// GRU encoder: B=128, K=512, I=512, H=512.
// R12: R11 structure with the register-spill fixed in gru_rec's bulk consume.
//   - R11 shipped VGPR_Count=132 against a ~170-reg live set: the 32xdwordx4
//     tagged-exchange burst spilled to scratch, putting HBM round-trips inside
//     the serial per-step chain (7.4us/step). R12 uses a rolling 16-load window
//     (64 regs in flight) with staged vmcnt(8) waits + immediate extraction,
//     and moves the 48 MFMAs OUT of the validation-retry loop (no speculative
//     accumulators, no LDS-read hoisting hazard).
//   - Everything else identical to R11: serialized G/R alternation (CH=64),
//     tagged u64 h-exchange (data carries step tag; no flags, no drain),
//     W_hh in XOR-swizzled LDS, 'out' doubles as f32 h-state carry.
// Workspace: [ xg 50,331,648 | hbt 524,288 ] = 50,855,936 B.

#define CH 64
#define XG_BYTES (CH * 128 * 1536 * 4)
#define HBT_BYTES (2 * 128 * 256 * 8)

typedef float  floatx4 __attribute__((ext_vector_type(4)));
typedef short  shortx8 __attribute__((ext_vector_type(8)));
typedef unsigned int uintx4 __attribute__((ext_vector_type(4)));

__device__ __forceinline__ unsigned short f2bf(float f) {
    unsigned int uu = __float_as_uint(f);
    uu = (uu + 0x7FFFu + ((uu >> 16) & 1u)) >> 16;   // RNE; finite normals only
    return (unsigned short)uu;
}

// ===================== REC KERNEL =====================
__global__ __launch_bounds__(256, 1)
void gru_rec(const float* __restrict__ xgR, const float* __restrict__ Whh,
             const float* __restrict__ bhh,
             unsigned long long* __restrict__ hbt, float* __restrict__ out,
             int kg0) {
    __shared__ unsigned short Wl[96 * 512];   // 96KB: rows g*32+lu, swizzled bf16 W_hh slice

    const int bx = blockIdx.x, t = threadIdx.x;
    const int wave = t >> 6, lane = t & 63, quad = lane >> 4, l16 = lane & 15;
    const int ug = bx & 15, bg = bx >> 4;
    const int u0 = ug * 32, b0 = bg * 32;
    const int mt = wave & 1, u16 = wave >> 1;
    const int b_base = b0 + mt * 16 + quad * 4;   // C rows = b_base + reg
    const int u = u0 + u16 * 16 + l16;            // this lane's unit column
    const int rrow = b0 + mt * 16 + l16;          // exchange A-fragment row

    // ---- stage W_hh slice -> LDS (bf16, swizzled) ----
    for (int i = t; i < 96 * 128; i += 256) {
        const int r = i >> 7, cq = i & 127;       // LDS row (g*32+lu), float4-chunk
        const int g = r >> 5, lu = r & 31;
        const float* p = Whh + ((size_t)(g * 512 + u0 + lu)) * 512 + cq * 4;
        float4 vv = *(const float4*)p;
        ushort4 b4;
        b4.x = f2bf(vv.x); b4.y = f2bf(vv.y); b4.z = f2bf(vv.z); b4.w = f2bf(vv.w);
        *(ushort4*)&Wl[r * 512 + ((cq * 4) ^ ((r & 7) << 3))] = b4;
    }
    __syncthreads();

    const float bhr = bhh[u], bhz = bhh[512 + u], bhn = bhh[1024 + u];
    const int rb = u16 * 16 + l16, xrw = (rb & 7) << 3;   // B-frag LDS row + swizzle

    float hp[4];
    if (kg0 == 0) {
        hp[0] = hp[1] = hp[2] = hp[3] = 0.f;
    } else {
        #pragma unroll
        for (int reg = 0; reg < 4; ++reg) hp[reg] = out[(size_t)(b_base + reg) * 512 + u];
    }

    for (int s = 0; s < CH; ++s) {
        const int kg = kg0 + s;
        // x-gate loads issue early; exchange poll hides their latency
        float xr[4], xz[4], xn[4];
        #pragma unroll
        for (int reg = 0; reg < 4; ++reg) {
            const float* xgp = xgR + ((size_t)s * 128 + b_base + reg) * 1536 + u;
            xr[reg] = xgp[0]; xz[reg] = xgp[512]; xn[reg] = xgp[1024];
        }

        union AF { unsigned int d[4]; shortx8 v; } af[16];
        if (kg > 0) {
            const unsigned int expv = (unsigned int)(kg - 1);
            const size_t pbase = (size_t)((kg - 1) & 1) * 32768;
            // stage 1: sampled-tag spin (1 load/lane; covers all 32 producer waves)
            const unsigned long long* sp = hbt + pbase + (size_t)rrow * 256
                                              + ((lane & 31) >> 1) * 16 + (lane & 1) * 8;
            for (;;) {
                unsigned int tg = (unsigned int)(__hip_atomic_load(sp, __ATOMIC_RELAXED,
                                                 __HIP_MEMORY_SCOPE_AGENT) >> 32);
                if (__ballot(tg != expv) == 0ull) break;
                __builtin_amdgcn_s_sleep(1);
            }
            // stage 2: rolling 16-load window (64 regs in flight), staged vmcnt(8)
            // waits, immediate extraction+validation. MFMAs are AFTER the loop.
            const unsigned long long* hbp = hbt + pbase + (size_t)rrow * 256 + quad * 4;
            union QT { uintx4 v; unsigned int d[4]; } Q[16];
            #define LDQ(i, OFF) asm volatile("global_load_dwordx4 %0, %1, off offset:" OFF " sc0 sc1" \
                    : "=v"(Q[i].v) : "v"(hbp) : "memory");
            #define WCNT(N) asm volatile("s_waitcnt vmcnt(" #N ")" ::: "memory"); \
                    __builtin_amdgcn_sched_barrier(0);
            #define EXT(kt, qa, qb) \
                    af[kt].d[0] = Q[qa].d[0]; af[kt].d[1] = Q[qa].d[2]; \
                    af[kt].d[2] = Q[qb].d[0]; af[kt].d[3] = Q[qb].d[2]; \
                    err |= (Q[qa].d[1] ^ expv) | (Q[qa].d[3] ^ expv) \
                         | (Q[qb].d[1] ^ expv) | (Q[qb].d[3] ^ expv);
            for (;;) {
                unsigned int err = 0u;
                // issue kt 0..7 (16 loads outstanding)
                LDQ(0,"0")    LDQ(1,"16")   LDQ(2,"128")  LDQ(3,"144")
                LDQ(4,"256")  LDQ(5,"272")  LDQ(6,"384")  LDQ(7,"400")
                LDQ(8,"512")  LDQ(9,"528")  LDQ(10,"640") LDQ(11,"656")
                LDQ(12,"768") LDQ(13,"784") LDQ(14,"896") LDQ(15,"912")
                WCNT(8)                    // kt 0..3 landed
                EXT(0, 0, 1)  EXT(1, 2, 3)  EXT(2, 4, 5)  EXT(3, 6, 7)
                // refill window: issue kt 8..11 into Q[0..7]
                LDQ(0,"1024") LDQ(1,"1040") LDQ(2,"1152") LDQ(3,"1168")
                LDQ(4,"1280") LDQ(5,"1296") LDQ(6,"1408") LDQ(7,"1424")
                WCNT(8)                    // kt 4..7 landed
                EXT(4, 8, 9)  EXT(5, 10, 11) EXT(6, 12, 13) EXT(7, 14, 15)
                // refill window: issue kt 12..15 into Q[8..15]
                LDQ(8,"1536")  LDQ(9,"1552")  LDQ(10,"1664") LDQ(11,"1680")
                LDQ(12,"1792") LDQ(13,"1808") LDQ(14,"1920") LDQ(15,"1936")
                WCNT(8)                    // kt 8..11 landed
                EXT(8, 0, 1)  EXT(9, 2, 3)  EXT(10, 4, 5)  EXT(11, 6, 7)
                WCNT(0)                    // kt 12..15 landed
                EXT(12, 8, 9) EXT(13, 10, 11) EXT(14, 12, 13) EXT(15, 14, 15)
                if (__ballot(err != 0u) == 0ull) break;   // rare retry
                __builtin_amdgcn_s_sleep(1);
            }
            #undef LDQ
            #undef WCNT
            #undef EXT
        } else {
            #pragma unroll
            for (int kt = 0; kt < 16; ++kt) {
                af[kt].d[0] = 0u; af[kt].d[1] = 0u; af[kt].d[2] = 0u; af[kt].d[3] = 0u;
            }
        }

        // ---- h-MFMA: 48 MFMAs; B-fragments streamed from swizzled LDS ----
        floatx4 aR = {0,0,0,0}, aZ = {0,0,0,0}, aN = {0,0,0,0};
        #pragma unroll
        for (int kt = 0; kt < 16; ++kt) {
            const int co = (kt * 32 + quad * 8) ^ xrw;
            shortx8 bR = *(const shortx8*)&Wl[(size_t)rb * 512 + co];
            shortx8 bZ = *(const shortx8*)&Wl[(size_t)(32 + rb) * 512 + co];
            shortx8 bN = *(const shortx8*)&Wl[(size_t)(64 + rb) * 512 + co];
            aR = __builtin_amdgcn_mfma_f32_16x16x32_bf16(af[kt].v, bR, aR, 0, 0, 0);
            aZ = __builtin_amdgcn_mfma_f32_16x16x32_bf16(af[kt].v, bZ, aZ, 0, 0, 0);
            aN = __builtin_amdgcn_mfma_f32_16x16x32_bf16(af[kt].v, bN, aN, 0, 0, 0);
        }

        // ---- activations + tagged publish (fire-and-forget, no drain) ----
        unsigned long long* hdst = hbt + (size_t)(kg & 1) * 32768;
        const unsigned long long tagv = ((unsigned long long)(unsigned int)kg) << 32;
        #pragma unroll
        for (int reg = 0; reg < 4; ++reg) {
            const float r = 1.f / (1.f + __expf(-(xr[reg] + aR[reg] + bhr)));
            const float z = 1.f / (1.f + __expf(-(xz[reg] + aZ[reg] + bhz)));
            const float nv = xn[reg] + r * (aN[reg] + bhn);
            const float n = 1.f - 2.f / (__expf(2.f * nv) + 1.f);   // fast tanh
            const float h = (1.f - z) * n + z * hp[reg];
            hp[reg] = h;
            const float h_odd = __shfl_xor(h, 1);
            if (!(lane & 1)) {
                unsigned long long val = tagv |
                    (unsigned long long)((unsigned int)f2bf(h) |
                                         ((unsigned int)f2bf(h_odd) << 16));
                __hip_atomic_store(hdst + (size_t)(b_base + reg) * 256 + (u >> 1), val,
                                   __ATOMIC_RELAXED, __HIP_MEMORY_SCOPE_AGENT);
            }
        }
    }

    // running h -> out (acts as hstate carry; final dispatch leaves h[511] here)
    #pragma unroll
    for (int reg = 0; reg < 4; ++reg)
        out[(size_t)(b_base + reg) * 512 + u] = hp[reg];
}

// ===================== GEMM KERNEL (x-gates for one 64-step chunk) =====================
__global__ __launch_bounds__(256)
void gemm_xg(const float* __restrict__ vis, const float* __restrict__ Wih,
             const float* __restrict__ bih, float* __restrict__ xgW, int gemm_kg0) {
    __shared__ unsigned short Ast[64][40];
    __shared__ unsigned short Bst[64][40];

    const int t = threadIdx.x;
    const int wave = t >> 6, lane = t & 63, quad = lane >> 4, l16 = lane & 15;

    for (int T = blockIdx.x; T < 24 * 128; T += gridDim.x) {   // 24 g-tiles x 128 m-tiles
        const int g0 = (T % 24) * 64;
        const int m0 = (T / 24) * 64;            // chunk-local m = kc*128 + b
        const int kc = m0 >> 7;                  // 0..63
        const int b0 = m0 & 127;
        const int kg = gemm_kg0 + kc;

        floatx4 acc[4] = {{0,0,0,0},{0,0,0,0},{0,0,0,0},{0,0,0,0}};

        for (int ki = 0; ki < 16; ++ki) {
            const int i0 = ki * 32;
            #pragma unroll
            for (int rep = 0; rep < 2; ++rep) {
                const int r = (t >> 3) + rep * 32;
                const int c = (t & 7) * 4;
                float4 av = *(const float4*)(vis + ((size_t)(b0 + r) * 512 + kg) * 512 + i0 + c);
                ushort4 ab; ab.x = f2bf(av.x); ab.y = f2bf(av.y); ab.z = f2bf(av.z); ab.w = f2bf(av.w);
                *(ushort4*)&Ast[r][c] = ab;
                float4 bv = *(const float4*)(Wih + (size_t)(g0 + r) * 512 + i0 + c);
                ushort4 bb; bb.x = f2bf(bv.x); bb.y = f2bf(bv.y); bb.z = f2bf(bv.z); bb.w = f2bf(bv.w);
                *(ushort4*)&Bst[r][c] = bb;
            }
            __syncthreads();
            shortx8 afr = *(const shortx8*)(&Ast[wave * 16 + l16][quad * 8]);
            #pragma unroll
            for (int nb = 0; nb < 4; ++nb) {
                shortx8 bfr = *(const shortx8*)(&Bst[nb * 16 + l16][quad * 8]);
                acc[nb] = __builtin_amdgcn_mfma_f32_16x16x32_bf16(afr, bfr, acc[nb], 0, 0, 0);
            }
            __syncthreads();
        }
        #pragma unroll
        for (int nb = 0; nb < 4; ++nb) {
            const int g = g0 + nb * 16 + l16;
            const float bi = bih[g];
            #pragma unroll
            for (int reg = 0; reg < 4; ++reg) {
                const int m = m0 + wave * 16 + quad * 4 + reg;
                xgW[(size_t)m * 1536 + g] = acc[nb][reg] + bi;
            }
        }
    }
}

extern "C" void kernel_launch(void* const* d_in, const int* in_sizes, int n_in,
                              void* d_out, int out_size, void* d_ws, size_t ws_size,
                              hipStream_t stream) {
    const float* vis = (const float*)d_in[0];
    const float* Wih = (const float*)d_in[1];
    const float* Whh = (const float*)d_in[2];
    const float* bih = (const float*)d_in[3];
    const float* bhh = (const float*)d_in[4];
    float* out = (float*)d_out;

    char* ws = (char*)d_ws;
    float* xg = (float*)ws;
    unsigned long long* hbt = (unsigned long long*)(ws + XG_BYTES);

    // 0xFF tags (0xFFFFFFFF) never match any step 0..511; re-armed every iteration
    // (prevents stale-tag aliasing at the parity buffer across bench replays).
    hipMemsetAsync(hbt, 0xFF, HBT_BYTES, stream);

    // Serialized alternation: G0, R0, G1, R1, ..., G7, R7. Single xg buffer —
    // stream order guarantees G(c+1) only overwrites after R(c) finished.
    gemm_xg<<<1536, 256, 0, stream>>>(vis, Wih, bih, xg, 0);
    for (int c = 0; c < 8; ++c) {
        gru_rec<<<64, 256, 0, stream>>>(xg, Whh, bhh, hbt, out, c * CH);
        if (c < 7)
            gemm_xg<<<1536, 256, 0, stream>>>(vis, Wih, bih, xg, (c + 1) * CH);
    }
}

// Round 7
// 3855.152 us; speedup vs baseline: 1.4825x; 1.1039x over previous
//
#include <hip/hip_runtime.h>

// GRU encoder: B=128, K=512, I=512, H=512.
// R13: per-tile validate/consume in gru_rec (structure otherwise = R11/R12).
//   - R11/R12 both re-loaded ALL 32 dwordx4 on ANY stale tag (~1us/pass) and
//     kept af[16]+Q[16] live together (spill, VGPR capped at 132). R13:
//     ping-pong groups of 4 tiles (Qa/Qb, 16 loads in flight); per-tile
//     ballot-validate; fresh tiles are MFMA'd DIRECTLY from Q (no af array);
//     stale tiles retried individually (2 loads + RT each).
//   - Serialized G/R alternation (CH=64), tagged u64 h-exchange (data carries
//     its step tag; no flags, no producer drain), W_hh in XOR-swizzled LDS,
//     'out' doubles as the f32 h-state carry.
// Workspace: [ xg 50,331,648 | hbt 524,288 ] = 50,855,936 B.

#define CH 64
#define XG_BYTES (CH * 128 * 1536 * 4)
#define HBT_BYTES (2 * 128 * 256 * 8)

typedef float  floatx4 __attribute__((ext_vector_type(4)));
typedef short  shortx8 __attribute__((ext_vector_type(8)));
typedef unsigned int uintx4 __attribute__((ext_vector_type(4)));

__device__ __forceinline__ unsigned short f2bf(float f) {
    unsigned int uu = __float_as_uint(f);
    uu = (uu + 0x7FFFu + ((uu >> 16) & 1u)) >> 16;   // RNE; finite normals only
    return (unsigned short)uu;
}

// ===================== REC KERNEL =====================
__global__ __launch_bounds__(256, 1)
void gru_rec(const float* __restrict__ xgR, const float* __restrict__ Whh,
             const float* __restrict__ bhh,
             unsigned long long* __restrict__ hbt, float* __restrict__ out,
             int kg0) {
    __shared__ unsigned short Wl[96 * 512];   // 96KB: rows g*32+lu, swizzled bf16 W_hh slice

    const int bx = blockIdx.x, t = threadIdx.x;
    const int wave = t >> 6, lane = t & 63, quad = lane >> 4, l16 = lane & 15;
    const int ug = bx & 15, bg = bx >> 4;
    const int u0 = ug * 32, b0 = bg * 32;
    const int mt = wave & 1, u16 = wave >> 1;
    const int b_base = b0 + mt * 16 + quad * 4;   // C rows = b_base + reg
    const int u = u0 + u16 * 16 + l16;            // this lane's unit column
    const int rrow = b0 + mt * 16 + l16;          // exchange A-fragment row

    // ---- stage W_hh slice -> LDS (bf16, swizzled) ----
    for (int i = t; i < 96 * 128; i += 256) {
        const int r = i >> 7, cq = i & 127;       // LDS row (g*32+lu), float4-chunk
        const int g = r >> 5, lu = r & 31;
        const float* p = Whh + ((size_t)(g * 512 + u0 + lu)) * 512 + cq * 4;
        float4 vv = *(const float4*)p;
        ushort4 b4;
        b4.x = f2bf(vv.x); b4.y = f2bf(vv.y); b4.z = f2bf(vv.z); b4.w = f2bf(vv.w);
        *(ushort4*)&Wl[r * 512 + ((cq * 4) ^ ((r & 7) << 3))] = b4;
    }
    __syncthreads();

    const float bhr = bhh[u], bhz = bhh[512 + u], bhn = bhh[1024 + u];
    const int rb = u16 * 16 + l16, xrw = (rb & 7) << 3;   // B-frag LDS row + swizzle

    float hp[4];
    if (kg0 == 0) {
        hp[0] = hp[1] = hp[2] = hp[3] = 0.f;
    } else {
        #pragma unroll
        for (int reg = 0; reg < 4; ++reg) hp[reg] = out[(size_t)(b_base + reg) * 512 + u];
    }

    for (int s = 0; s < CH; ++s) {
        const int kg = kg0 + s;
        // x-gate loads issue early; exchange poll hides their latency
        float xr[4], xz[4], xn[4];
        #pragma unroll
        for (int reg = 0; reg < 4; ++reg) {
            const float* xgp = xgR + ((size_t)s * 128 + b_base + reg) * 1536 + u;
            xr[reg] = xgp[0]; xz[reg] = xgp[512]; xn[reg] = xgp[1024];
        }

        floatx4 aR = {0,0,0,0}, aZ = {0,0,0,0}, aN = {0,0,0,0};

        if (kg > 0) {
            const unsigned int expv = (unsigned int)(kg - 1);
            const size_t pbase = (size_t)((kg - 1) & 1) * 32768;
            // stage 1: sampled-tag spin (1 load/lane; covers all 32 producer waves,
            // rows 0..15 across lanes cover every producer's last store instruction)
            const unsigned long long* sp = hbt + pbase + (size_t)rrow * 256
                                              + ((lane & 31) >> 1) * 16 + (lane & 1) * 8;
            for (;;) {
                unsigned int tg = (unsigned int)(__hip_atomic_load(sp, __ATOMIC_RELAXED,
                                                 __HIP_MEMORY_SCOPE_AGENT) >> 32);
                if (__ballot(tg != expv) == 0ull) break;
                __builtin_amdgcn_s_sleep(1);
            }
            // stage 2: ping-pong groups of 4 tiles; per-tile validate; MFMA fresh
            // tiles directly from Q (no af[] array => no spill); retry stale only.
            const unsigned long long* hbp = hbt + pbase + (size_t)rrow * 256 + quad * 4;
            union QT { uintx4 v; unsigned int d[4]; } Qa[8], Qb[8];
            unsigned int done = 0u;

            #define LDQA(i, OFF) asm volatile("global_load_dwordx4 %0, %1, off offset:" OFF " sc0 sc1" \
                    : "=v"(Qa[i].v) : "v"(hbp) : "memory");
            #define LDQB(i, OFF) asm volatile("global_load_dwordx4 %0, %1, off offset:" OFF " sc0 sc1" \
                    : "=v"(Qb[i].v) : "v"(hbp) : "memory");
            #define WCNT(N) asm volatile("s_waitcnt vmcnt(" #N ")" ::: "memory"); \
                    __builtin_amdgcn_sched_barrier(0);
            #define PROC(q0, q1, KT) { \
                unsigned int e = (q0.d[1] ^ expv) | (q0.d[3] ^ expv) \
                               | (q1.d[1] ^ expv) | (q1.d[3] ^ expv); \
                if (__ballot(e != 0u) == 0ull) { \
                    union { unsigned int d[4]; shortx8 v; } afu; \
                    afu.d[0] = q0.d[0]; afu.d[1] = q0.d[2]; \
                    afu.d[2] = q1.d[0]; afu.d[3] = q1.d[2]; \
                    const int co = ((KT) * 32 + quad * 8) ^ xrw; \
                    shortx8 bRf = *(const shortx8*)&Wl[(size_t)rb * 512 + co]; \
                    shortx8 bZf = *(const shortx8*)&Wl[(size_t)(32 + rb) * 512 + co]; \
                    shortx8 bNf = *(const shortx8*)&Wl[(size_t)(64 + rb) * 512 + co]; \
                    aR = __builtin_amdgcn_mfma_f32_16x16x32_bf16(afu.v, bRf, aR, 0, 0, 0); \
                    aZ = __builtin_amdgcn_mfma_f32_16x16x32_bf16(afu.v, bZf, aZ, 0, 0, 0); \
                    aN = __builtin_amdgcn_mfma_f32_16x16x32_bf16(afu.v, bNf, aN, 0, 0, 0); \
                    done |= (1u << (KT)); \
                } }

            // first pass: tiles 0..15 in 4 groups, 16 loads in flight
            LDQA(0,"0")    LDQA(1,"16")   LDQA(2,"128")  LDQA(3,"144")
            LDQA(4,"256")  LDQA(5,"272")  LDQA(6,"384")  LDQA(7,"400")
            LDQB(0,"512")  LDQB(1,"528")  LDQB(2,"640")  LDQB(3,"656")
            LDQB(4,"768")  LDQB(5,"784")  LDQB(6,"896")  LDQB(7,"912")
            WCNT(8)   // group 0 landed
            PROC(Qa[0], Qa[1], 0) PROC(Qa[2], Qa[3], 1)
            PROC(Qa[4], Qa[5], 2) PROC(Qa[6], Qa[7], 3)
            LDQA(0,"1024") LDQA(1,"1040") LDQA(2,"1152") LDQA(3,"1168")
            LDQA(4,"1280") LDQA(5,"1296") LDQA(6,"1408") LDQA(7,"1424")
            WCNT(8)   // group 1 landed
            PROC(Qb[0], Qb[1], 4) PROC(Qb[2], Qb[3], 5)
            PROC(Qb[4], Qb[5], 6) PROC(Qb[6], Qb[7], 7)
            LDQB(0,"1536") LDQB(1,"1552") LDQB(2,"1664") LDQB(3,"1680")
            LDQB(4,"1792") LDQB(5,"1808") LDQB(6,"1920") LDQB(7,"1936")
            WCNT(8)   // group 2 landed
            PROC(Qa[0], Qa[1], 8)  PROC(Qa[2], Qa[3], 9)
            PROC(Qa[4], Qa[5], 10) PROC(Qa[6], Qa[7], 11)
            WCNT(0)   // group 3 landed
            PROC(Qb[0], Qb[1], 12) PROC(Qb[2], Qb[3], 13)
            PROC(Qb[4], Qb[5], 14) PROC(Qb[6], Qb[7], 15)

            // retry stale tiles individually (rare; one small RT each)
            while (done != 0xFFFFu) {
                for (int kt = 0; kt < 16; ++kt) {
                    if (done & (1u << kt)) continue;
                    const unsigned long long* tp = hbp + (size_t)kt * 16;
                    asm volatile("global_load_dwordx4 %0, %1, off offset:0 sc0 sc1"
                                 : "=v"(Qa[0].v) : "v"(tp) : "memory");
                    asm volatile("global_load_dwordx4 %0, %1, off offset:16 sc0 sc1"
                                 : "=v"(Qa[1].v) : "v"(tp) : "memory");
                    WCNT(0)
                    PROC(Qa[0], Qa[1], kt)
                }
            }
            #undef LDQA
            #undef LDQB
            #undef WCNT
            #undef PROC
        }
        // kg==0: h(-1)=0 => aR/aZ/aN stay 0, no consume needed.

        // ---- activations + tagged publish (fire-and-forget, no drain) ----
        unsigned long long* hdst = hbt + (size_t)(kg & 1) * 32768;
        const unsigned long long tagv = ((unsigned long long)(unsigned int)kg) << 32;
        #pragma unroll
        for (int reg = 0; reg < 4; ++reg) {
            const float r = 1.f / (1.f + __expf(-(xr[reg] + aR[reg] + bhr)));
            const float z = 1.f / (1.f + __expf(-(xz[reg] + aZ[reg] + bhz)));
            const float nv = xn[reg] + r * (aN[reg] + bhn);
            const float n = 1.f - 2.f / (__expf(2.f * nv) + 1.f);   // fast tanh
            const float h = (1.f - z) * n + z * hp[reg];
            hp[reg] = h;
            const float h_odd = __shfl_xor(h, 1);
            if (!(lane & 1)) {
                unsigned long long val = tagv |
                    (unsigned long long)((unsigned int)f2bf(h) |
                                         ((unsigned int)f2bf(h_odd) << 16));
                __hip_atomic_store(hdst + (size_t)(b_base + reg) * 256 + (u >> 1), val,
                                   __ATOMIC_RELAXED, __HIP_MEMORY_SCOPE_AGENT);
            }
        }
    }

    // running h -> out (acts as hstate carry; final dispatch leaves h[511] here)
    #pragma unroll
    for (int reg = 0; reg < 4; ++reg)
        out[(size_t)(b_base + reg) * 512 + u] = hp[reg];
}

// ===================== GEMM KERNEL (x-gates for one 64-step chunk) =====================
__global__ __launch_bounds__(256)
void gemm_xg(const float* __restrict__ vis, const float* __restrict__ Wih,
             const float* __restrict__ bih, float* __restrict__ xgW, int gemm_kg0) {
    __shared__ unsigned short Ast[64][40];
    __shared__ unsigned short Bst[64][40];

    const int t = threadIdx.x;
    const int wave = t >> 6, lane = t & 63, quad = lane >> 4, l16 = lane & 15;

    for (int T = blockIdx.x; T < 24 * 128; T += gridDim.x) {   // 24 g-tiles x 128 m-tiles
        const int g0 = (T % 24) * 64;
        const int m0 = (T / 24) * 64;            // chunk-local m = kc*128 + b
        const int kc = m0 >> 7;                  // 0..63
        const int b0 = m0 & 127;
        const int kg = gemm_kg0 + kc;

        floatx4 acc[4] = {{0,0,0,0},{0,0,0,0},{0,0,0,0},{0,0,0,0}};

        for (int ki = 0; ki < 16; ++ki) {
            const int i0 = ki * 32;
            #pragma unroll
            for (int rep = 0; rep < 2; ++rep) {
                const int r = (t >> 3) + rep * 32;
                const int c = (t & 7) * 4;
                float4 av = *(const float4*)(vis + ((size_t)(b0 + r) * 512 + kg) * 512 + i0 + c);
                ushort4 ab; ab.x = f2bf(av.x); ab.y = f2bf(av.y); ab.z = f2bf(av.z); ab.w = f2bf(av.w);
                *(ushort4*)&Ast[r][c] = ab;
                float4 bv = *(const float4*)(Wih + (size_t)(g0 + r) * 512 + i0 + c);
                ushort4 bb; bb.x = f2bf(bv.x); bb.y = f2bf(bv.y); bb.z = f2bf(bv.z); bb.w = f2bf(bv.w);
                *(ushort4*)&Bst[r][c] = bb;
            }
            __syncthreads();
            shortx8 afr = *(const shortx8*)(&Ast[wave * 16 + l16][quad * 8]);
            #pragma unroll
            for (int nb = 0; nb < 4; ++nb) {
                shortx8 bfr = *(const shortx8*)(&Bst[nb * 16 + l16][quad * 8]);
                acc[nb] = __builtin_amdgcn_mfma_f32_16x16x32_bf16(afr, bfr, acc[nb], 0, 0, 0);
            }
            __syncthreads();
        }
        #pragma unroll
        for (int nb = 0; nb < 4; ++nb) {
            const int g = g0 + nb * 16 + l16;
            const float bi = bih[g];
            #pragma unroll
            for (int reg = 0; reg < 4; ++reg) {
                const int m = m0 + wave * 16 + quad * 4 + reg;
                xgW[(size_t)m * 1536 + g] = acc[nb][reg] + bi;
            }
        }
    }
}

extern "C" void kernel_launch(void* const* d_in, const int* in_sizes, int n_in,
                              void* d_out, int out_size, void* d_ws, size_t ws_size,
                              hipStream_t stream) {
    const float* vis = (const float*)d_in[0];
    const float* Wih = (const float*)d_in[1];
    const float* Whh = (const float*)d_in[2];
    const float* bih = (const float*)d_in[3];
    const float* bhh = (const float*)d_in[4];
    float* out = (float*)d_out;

    char* ws = (char*)d_ws;
    float* xg = (float*)ws;
    unsigned long long* hbt = (unsigned long long*)(ws + XG_BYTES);

    // 0xFF tags (0xFFFFFFFF) never match any step 0..511; re-armed every iteration
    // (prevents stale-tag aliasing at the parity buffer across bench replays).
    hipMemsetAsync(hbt, 0xFF, HBT_BYTES, stream);

    // Serialized alternation: G0, R0, G1, R1, ..., G7, R7. Single xg buffer —
    // stream order guarantees G(c+1) only overwrites after R(c) finished.
    gemm_xg<<<1536, 256, 0, stream>>>(vis, Wih, bih, xg, 0);
    for (int c = 0; c < 8; ++c) {
        gru_rec<<<64, 256, 0, stream>>>(xg, Whh, bhh, hbt, out, c * CH);
        if (c < 7)
            gemm_xg<<<1536, 256, 0, stream>>>(vis, Wih, bih, xg, (c + 1) * CH);
    }
}